// Round 3
// baseline (360.480 us; speedup 1.0000x reference)
//
#include <hip/hip_runtime.h>
#include <hip/hip_bf16.h>

// PointerNet: out[b][k] = sum_c C_k[b,c] * sigmoid(WP[b,c]+WC_k[b,c]+Gb[c]) * (WPo[b,c]+Ob[c])
//   GEMM A: WPcat = P @ [GateWeight_P | OutWeight]  (M=8192,N=2048,K=1024), output INTERLEAVED:
//           uint32 WPcat[b][c] = (bf16 wp, bf16 wpo) so the epilogue gets both in one load.
//   GEMM B: WC_k = C_k @ GateWeight_C fused with sigmoid/dot epilogue (atomicAdd out).
// R8: R7 post-mortem showed T4-without-T3: counted vmcnt ring worked (conflicts 0, no
//     drain) but bulk {12 ds_read; 32 MFMA} per K-tile left MfmaUtil at 16.6% — the
//     LDS-read block and the MFMA block serialize when all waves are in the same bulk
//     phase (matches m233's 2-phase stall). Fix: 4 phases per K-tile (m201 skeleton):
//     each phase {2-6 ds_read_b128 (+2 gl_lds in ph0/ph1) ; s_barrier ; setprio(1) ;
//     8 MFMA ; setprio(0) ; s_barrier}, 8 barriers/K-tile. Reads are C++ loads so the
//     compiler emits fine-grained partial lgkmcnt inside each MFMA cluster;
//     sched_barrier(0) after each s_barrier pins phase boundaries (rule #18).
//     vmcnt(8) ledger unchanged; ring 4 x 32KB = 128KB.

#define B_  8192
#define PD_ 1024
#define CD_ 1024

typedef unsigned short ushort_t;
typedef unsigned int   uint_t;
typedef __attribute__((ext_vector_type(8))) short    short8;
typedef __attribute__((ext_vector_type(4))) float    floatx4;

__device__ __forceinline__ float bf2f(unsigned short u) {
    return __uint_as_float(((unsigned)u) << 16);
}
__device__ __forceinline__ unsigned short f2bf(float f) {
    unsigned u = __float_as_uint(f);
    unsigned r = u + 0x7FFFu + ((u >> 16) & 1u);   // RNE
    return (unsigned short)(r >> 16);
}

// ---------------- prep: cast P,C1..C4 -> bf16; transpose 3 weights; zero out ----------------
__global__ __launch_bounds__(256) void prep_kernel(const float* __restrict__ P,
                                                   const float* __restrict__ C1,
                                                   const float* __restrict__ C2,
                                                   const float* __restrict__ C3,
                                                   const float* __restrict__ C4,
                                                   const float* __restrict__ GWP,
                                                   const float* __restrict__ OW,
                                                   const float* __restrict__ GWC,
                                                   ushort_t* __restrict__ Pb,
                                                   ushort_t* __restrict__ Call,
                                                   ushort_t* __restrict__ Wcat,
                                                   ushort_t* __restrict__ GWCt,
                                                   float* __restrict__ out) {
    const int bid = blockIdx.x;
    const int tid = threadIdx.x;
    if (bid < 40960) {
        const int seg = bid >> 13;
        const int i   = (bid & 8191) * 256 + tid;
        const float* src;
        ushort_t* dst;
        switch (seg) {
            case 0: src = P;  dst = Pb; break;
            case 1: src = C1; dst = Call; break;
            case 2: src = C2; dst = Call + (size_t)1 * B_ * CD_; break;
            case 3: src = C3; dst = Call + (size_t)2 * B_ * CD_; break;
            default: src = C4; dst = Call + (size_t)3 * B_ * CD_; break;
        }
        float4 v = ((const float4*)src)[i];
        ushort4 o;
        o.x = f2bf(v.x); o.y = f2bf(v.y); o.z = f2bf(v.z); o.w = f2bf(v.w);
        ((ushort4*)dst)[i] = o;
    } else if (bid < 44032) {
        __shared__ float tile[32][33];
        const int tb  = bid - 40960;
        const int seg = tb >> 10;
        const int t32 = tb & 1023;
        const float* src;
        ushort_t* dst;
        switch (seg) {
            case 0: src = GWP; dst = Wcat; break;
            case 1: src = OW;  dst = Wcat + 1024 * 1024; break;
            default: src = GWC; dst = GWCt; break;
        }
        const int c0 = (t32 & 31) * 32, r0 = (t32 >> 5) * 32;
        const int x = tid & 31, y = tid >> 5;
        for (int i = y; i < 32; i += 8)
            tile[i][x] = src[(size_t)(r0 + i) * 1024 + c0 + x];
        __syncthreads();
        for (int i = y; i < 32; i += 8)
            dst[(size_t)(c0 + i) * 1024 + r0 + x] = f2bf(tile[x][i]);
    } else {
        const int i = (bid - 44032) * 256 + tid;
        ((float4*)out)[i] = float4{0.f, 0.f, 0.f, 0.f};
    }
}

__device__ __forceinline__ void gl_lds16(const void* g, void* l) {
    __builtin_amdgcn_global_load_lds((const __attribute__((address_space(1))) void*)g,
                                     (__attribute__((address_space(3))) void*)l, 16, 0, 0);
}

#define VM8()  asm volatile("s_waitcnt vmcnt(8)" ::: "memory")
#define VM4()  asm volatile("s_waitcnt vmcnt(4)" ::: "memory")
#define VM0()  asm volatile("s_waitcnt vmcnt(0)" ::: "memory")
#define BARR() __builtin_amdgcn_s_barrier()
#define SB0()  __builtin_amdgcn_sched_barrier(0)

// ---------------- common 256x256 / BK=32 / 4-deep-ring / 4-phase pipelined K-loop ----------------
// LDS buffer kt&3: A tile 256x32 at base, B tile 256x32 at base+8192 (elems). Swizzle:
// 16B segment stored at seg_lds = seg_global ^ ((row>>1)&3)  (involution, both sides).
// vmcnt ledger (4 gl_lds per K-tile, split 2+2 over phases 0/1): at iter-t top,
// outstanding <= stages t+1,t+2 (8 loads) + unretired older; VM8 => stage-t retired
// (in-order VMEM retirement); top barrier publishes across waves.
// LDS ledger: stage(t+3) writes (issued after iter-t top barrier) target buf (t-1)&3;
// every wave's reads of buf (t-1) were lgkm-waited before its iter-(t-1) MFMAs, hence
// complete before it crossed the iter-t top barrier. Tail: VM8/VM8/VM4/VM0.
__device__ __forceinline__ void gemm256_pipeline(const ushort_t* __restrict__ A,
                                                 const ushort_t* __restrict__ Bt,
                                                 int tileM, int tileN,
                                                 ushort_t* smem,
                                                 floatx4 (&acc)[8][4]) {
    const int K = 1024;
    const int t = threadIdx.x;
    const int w = t >> 6, lane = t & 63;
    const int quad = lane >> 4, l16 = lane & 15;
    const int wm = w >> 2, wn = w & 3;

    // staging: wave w, load i in {0,1} covers rows w*16 + (lane>>2) + i*128 of each tile;
    // global 16B-segment pre-swizzled so LDS dest stays linear (rule #21).
    const int segg = ((lane & 3) ^ ((lane >> 3) & 3)) * 8;
    const ushort_t* Ap0 = A  + (size_t)(tileM + w * 16 + (lane >> 2)) * K + segg;
    const ushort_t* Ap1 = Ap0 + (size_t)128 * K;
    const ushort_t* Bp0 = Bt + (size_t)(tileN + w * 16 + (lane >> 2)) * K + segg;
    const ushort_t* Bp1 = Bp0 + (size_t)128 * K;
    const int lA0 = w * 512 + lane * 8;        // elem offsets within a ring buffer
    const int lA1 = lA0 + 4096;
    const int lB0 = 8192 + lA0;
    const int lB1 = lB0 + 4096;

    // fragment reads: row = (wm*128|wn*64) + {mi,ni}*16 + l16, k-seg quad, swizzled.
    const int xs  = (quad ^ ((l16 >> 1) & 3)) * 8;
    const int roA = (wm * 128 + l16) * 32 + xs;
    const int roB = 8192 + (wn * 64 + l16) * 32 + xs;

#pragma unroll
    for (int i = 0; i < 8; i++)
#pragma unroll
        for (int j = 0; j < 4; j++) acc[i][j] = (floatx4)0.f;

#define RD8(off) (*(const short8*)&smem[(off)])

#define STG_A(skt) do { const int b2_ = ((skt) & 3) * 16384; const int k2_ = (skt) * 32; \
        gl_lds16(Ap0 + k2_, &smem[b2_ + lA0]);                                           \
        gl_lds16(Ap1 + k2_, &smem[b2_ + lA1]); } while (0)
#define STG_B(skt) do { const int b2_ = ((skt) & 3) * 16384; const int k2_ = (skt) * 32; \
        gl_lds16(Bp0 + k2_, &smem[b2_ + lB0]);                                           \
        gl_lds16(Bp1 + k2_, &smem[b2_ + lB1]); } while (0)
#define STG4(skt) do { STG_A(skt); STG_B(skt); } while (0)

#define MM(mi_, a_) do { _Pragma("unroll")                                    \
        for (int ni = 0; ni < 4; ni++)                                        \
            acc[mi_][ni] = __builtin_amdgcn_mfma_f32_16x16x32_bf16(           \
                (a_), bf_[ni], acc[mi_][ni], 0, 0, 0); } while (0)

// one K-tile = 4 phases; 8 barriers; stage split over phases 0/1.
#define KSTEP(kt_, skt_, DOSTG_, VMW_) do {                                   \
        const int cb_ = ((kt_) & 3) * 16384;                                  \
        short8 bf_[4], a0_, a1_;                                              \
        VMW_; BARR(); SB0();                                                  \
        _Pragma("unroll")                                                     \
        for (int ni = 0; ni < 4; ni++) bf_[ni] = RD8(cb_ + roB + ni * 512);   \
        a0_ = RD8(cb_ + roA + 0 * 512); a1_ = RD8(cb_ + roA + 1 * 512);       \
        if (DOSTG_) STG_A(skt_);                                              \
        BARR(); SB0();                                                        \
        __builtin_amdgcn_s_setprio(1); MM(0, a0_); MM(1, a1_);                \
        __builtin_amdgcn_s_setprio(0);                                        \
        BARR(); SB0();                                                        \
        a0_ = RD8(cb_ + roA + 2 * 512); a1_ = RD8(cb_ + roA + 3 * 512);       \
        if (DOSTG_) STG_B(skt_);                                              \
        BARR(); SB0();                                                        \
        __builtin_amdgcn_s_setprio(1); MM(2, a0_); MM(3, a1_);                \
        __builtin_amdgcn_s_setprio(0);                                        \
        BARR(); SB0();                                                        \
        a0_ = RD8(cb_ + roA + 4 * 512); a1_ = RD8(cb_ + roA + 5 * 512);       \
        BARR(); SB0();                                                        \
        __builtin_amdgcn_s_setprio(1); MM(4, a0_); MM(5, a1_);                \
        __builtin_amdgcn_s_setprio(0);                                        \
        BARR(); SB0();                                                        \
        a0_ = RD8(cb_ + roA + 6 * 512); a1_ = RD8(cb_ + roA + 7 * 512);       \
        BARR(); SB0();                                                        \
        __builtin_amdgcn_s_setprio(1); MM(6, a0_); MM(7, a1_);                \
        __builtin_amdgcn_s_setprio(0);                                        \
    } while (0)

    STG4(0); STG4(1); STG4(2);
    for (int kt = 0; kt < 28; ++kt) {
        KSTEP(kt, kt + 3, 1, VM8());
    }
    KSTEP(28, 31, 1, VM8());
    KSTEP(29, 0, 0, VM8());
    KSTEP(30, 0, 0, VM4());
    KSTEP(31, 0, 0, VM0());
#undef KSTEP
#undef MM
#undef STG4
#undef STG_B
#undef STG_A
#undef RD8
}

// ---------------- GEMM A: WPcat(interleaved) = Pb @ Wcat^T  (256x256 tile, 512 thr) ----------------
// grid 256: xcd=bid&7, q=bid>>3; slab=(q>>3)*8+xcd (32 slabs), colt=q&7 (8 col tiles).
__global__ __launch_bounds__(512, 2) void gemmA_k(const ushort_t* __restrict__ A,
                                                  const ushort_t* __restrict__ Bt,
                                                  ushort_t* __restrict__ C) {
    __shared__ ushort_t smem[65536];     // 128 KB: 4 ring buffers x (A 8192 + B 8192 elems)
    const int xcd = blockIdx.x & 7, q = blockIdx.x >> 3;
    const int tileM = ((q >> 3) * 8 + xcd) * 256;
    const int tileN = (q & 7) * 256;

    floatx4 acc[8][4];
    gemm256_pipeline(A, Bt, tileM, tileN, smem, acc);

    const int t = threadIdx.x, lane = t & 63, quad = lane >> 4, l16 = lane & 15;
    const int w = t >> 6, wm = w >> 2, wn = w & 3;
    const int rowb = tileM + wm * 128 + quad * 4;
#pragma unroll
    for (int mi = 0; mi < 8; mi++)
#pragma unroll
        for (int ni = 0; ni < 4; ni++) {
            const int col = tileN + wn * 64 + ni * 16 + l16;
            const int ci = col & 1023, hi = col >> 10;    // interleave: (wp,wpo) per uint32
#pragma unroll
            for (int r = 0; r < 4; r++) {
                const int row = rowb + mi * 16 + r;
                C[(size_t)(row * 1024 + ci) * 2 + hi] = f2bf(acc[mi][ni][r]);
            }
        }
}

// ---------------- GEMM B + register-direct fused epilogue (256x256 tile, 512 thr) ----------------
// grid 512: xcd=bid&7, q=bid>>3; slab=(q>>2)*8+xcd (128 slabs), colt=q&3 (4 col tiles).
__global__ __launch_bounds__(512, 2) void gemmB_fused(const ushort_t* __restrict__ Call,
                                                      const ushort_t* __restrict__ GWCt,
                                                      const uint_t* __restrict__ WPcat,
                                                      const float* __restrict__ Gb,
                                                      const float* __restrict__ Ob,
                                                      float* __restrict__ out) {
    __shared__ ushort_t smem[65536];     // 128 KB ring
    const int xcd = blockIdx.x & 7, q = blockIdx.x >> 3;
    const int tileM = ((q >> 2) * 8 + xcd) * 256;
    const int tileN = (q & 3) * 256;

    floatx4 acc[8][4];
    gemm256_pipeline(Call, GWCt, tileM, tileN, smem, acc);

    const int t = threadIdx.x, lane = t & 63, quad = lane >> 4, l16 = lane & 15;
    const int w = t >> 6, wm = w >> 2, wn = w & 3;

    const int kk    = tileM >> 13;                         // choice index (uniform per block)
    const int b0    = (tileM & 8191) + wm * 128 + quad * 4;  // batch row base (+mi*16+r)
    const int rowg0 = tileM + wm * 128 + quad * 4;           // Call row base (+mi*16+r)

    float gbv[4], obv[4];
    int   gcol[4];
#pragma unroll
    for (int ni = 0; ni < 4; ni++) {
        gcol[ni] = tileN + wn * 64 + ni * 16 + l16;
        gbv[ni]  = Gb[gcol[ni]];
        obv[ni]  = Ob[gcol[ni]];
    }

#pragma unroll
    for (int mi = 0; mi < 8; mi++) {
        float part[4] = {0.f, 0.f, 0.f, 0.f};
#pragma unroll
        for (int ni = 0; ni < 4; ni++) {
            const uint_t*   wpp = WPcat + (size_t)(b0 + mi * 16) * 1024 + gcol[ni];
            const ushort_t* ckp = Call  + (size_t)(rowg0 + mi * 16) * 1024 + gcol[ni];
#pragma unroll
            for (int r = 0; r < 4; r++) {
                const uint_t wpair = wpp[(size_t)r * 1024];
                const float wp  = bf2f((unsigned short)(wpair & 0xffffu));
                const float wpo = bf2f((unsigned short)(wpair >> 16));
                const float ck  = bf2f(ckp[(size_t)r * 1024]);
                const float x = wp + acc[mi][ni][r] + gbv[ni];   // WC stays fp32
                const float g = 1.f / (1.f + __expf(-x));
                part[r] += ck * g * (wpo + obv[ni]);
            }
        }
#pragma unroll
        for (int r = 0; r < 4; r++) {                    // reduce across 16-lane quad group
            part[r] += __shfl_xor(part[r], 1);
            part[r] += __shfl_xor(part[r], 2);
            part[r] += __shfl_xor(part[r], 4);
            part[r] += __shfl_xor(part[r], 8);
        }
        if (l16 == 0) {
#pragma unroll
            for (int r = 0; r < 4; r++)
                atomicAdd(&out[(size_t)(b0 + mi * 16 + r) * 4 + kk], part[r]);
        }
    }
}

extern "C" void kernel_launch(void* const* d_in, const int* in_sizes, int n_in,
                              void* d_out, int out_size, void* d_ws, size_t ws_size,
                              hipStream_t stream) {
    (void)in_sizes; (void)n_in; (void)out_size; (void)ws_size;
    const float* P   = (const float*)d_in[0];
    const float* C1  = (const float*)d_in[1];
    const float* C2  = (const float*)d_in[2];
    const float* C3  = (const float*)d_in[3];
    const float* C4  = (const float*)d_in[4];
    const float* GWP = (const float*)d_in[5];
    const float* GWC = (const float*)d_in[6];
    const float* Gb  = (const float*)d_in[7];
    const float* OW  = (const float*)d_in[8];
    const float* Ob  = (const float*)d_in[9];
    float* out = (float*)d_out;

    // workspace (bf16): Pb 16MiB | Call 64MiB | Wcat 4MiB | GWCt 2MiB | WPcat 32MiB
    char* ws = (char*)d_ws;
    ushort_t* Pb    = (ushort_t*)(ws);
    ushort_t* Call  = (ushort_t*)(ws + (16u << 20));
    ushort_t* Wcat  = (ushort_t*)(ws + (80u << 20));
    ushort_t* GWCt  = (ushort_t*)(ws + (84u << 20));
    ushort_t* WPcat = (ushort_t*)(ws + (86u << 20));

    prep_kernel<<<44064, 256, 0, stream>>>(P, C1, C2, C3, C4, GWP, OW, GWC,
                                           Pb, Call, Wcat, GWCt, out);
    gemmA_k<<<256, 512, 0, stream>>>(Pb, Wcat, WPcat);
    gemmB_fused<<<512, 512, 0, stream>>>(Call, GWCt, (const uint_t*)WPcat, Gb, Ob, out);
}

// Round 4
// 345.408 us; speedup vs baseline: 1.0436x; 1.0436x over previous
//
#include <hip/hip_runtime.h>
#include <hip/hip_bf16.h>

// PointerNet: out[b][k] = sum_c C_k[b,c] * sigmoid(WP[b,c]+WC_k[b,c]+Gb[c]) * (WPo[b,c]+Ob[c])
//   GEMM A: WPcat = P @ [GateWeight_P | OutWeight]  (M=8192,N=2048,K=1024), output INTERLEAVED:
//           uint32 WPcat[b][c] = (bf16 wp, bf16 wpo) so the epilogue gets both in one load.
//   GEMM B: WC_k = C_k @ GateWeight_C fused with sigmoid/dot epilogue (atomicAdd out).
// R9: revert to the proven R5 skeleton (128x256 tile, 24KB LDS, multi-block/CU, simple
//     2-barrier K-loop = 116us gemmB) after two 256^2/128KB deep-pipeline attempts both
//     regressed (138/169us at 1 block/CU, occupancy 20% vs 37.5%). Grafted-on verified
//     wins only:
//     (1) conflict-free LDS swizzle from R7/R8 (slot = seg ^ ((row>>1)&3), measured
//         SQ_LDS_BANK_CONFLICT 8.4M -> 0); R5's (row>>2) variant serialized 4-8 way.
//     (2) interleaved WPcat write in gemmA + u32 wp/wpo epilogue loads in gemmB,
//         Gb/Ob hoisted per-ni (192 -> 128 epilogue loads/lane; verified R7/R8,
//         absmax unchanged).
//     Everything else byte-identical to the 341us baseline.

#define B_  8192
#define PD_ 1024
#define CD_ 1024

typedef unsigned short ushort_t;
typedef unsigned int   uint_t;
typedef __attribute__((ext_vector_type(8))) short    short8;
typedef __attribute__((ext_vector_type(4))) float    floatx4;

__device__ __forceinline__ float bf2f(unsigned short u) {
    return __uint_as_float(((unsigned)u) << 16);
}
__device__ __forceinline__ unsigned short f2bf(float f) {
    unsigned u = __float_as_uint(f);
    unsigned r = u + 0x7FFFu + ((u >> 16) & 1u);   // RNE
    return (unsigned short)(r >> 16);
}

// ---------------- prep: cast P,C1..C4 -> bf16; transpose 3 weights; zero out ----------------
__global__ __launch_bounds__(256) void prep_kernel(const float* __restrict__ P,
                                                   const float* __restrict__ C1,
                                                   const float* __restrict__ C2,
                                                   const float* __restrict__ C3,
                                                   const float* __restrict__ C4,
                                                   const float* __restrict__ GWP,
                                                   const float* __restrict__ OW,
                                                   const float* __restrict__ GWC,
                                                   ushort_t* __restrict__ Pb,
                                                   ushort_t* __restrict__ Call,
                                                   ushort_t* __restrict__ Wcat,
                                                   ushort_t* __restrict__ GWCt,
                                                   float* __restrict__ out) {
    const int bid = blockIdx.x;
    const int tid = threadIdx.x;
    if (bid < 40960) {
        const int seg = bid >> 13;
        const int i   = (bid & 8191) * 256 + tid;
        const float* src;
        ushort_t* dst;
        switch (seg) {
            case 0: src = P;  dst = Pb; break;
            case 1: src = C1; dst = Call; break;
            case 2: src = C2; dst = Call + (size_t)1 * B_ * CD_; break;
            case 3: src = C3; dst = Call + (size_t)2 * B_ * CD_; break;
            default: src = C4; dst = Call + (size_t)3 * B_ * CD_; break;
        }
        float4 v = ((const float4*)src)[i];
        ushort4 o;
        o.x = f2bf(v.x); o.y = f2bf(v.y); o.z = f2bf(v.z); o.w = f2bf(v.w);
        ((ushort4*)dst)[i] = o;
    } else if (bid < 44032) {
        __shared__ float tile[32][33];
        const int tb  = bid - 40960;
        const int seg = tb >> 10;
        const int t32 = tb & 1023;
        const float* src;
        ushort_t* dst;
        switch (seg) {
            case 0: src = GWP; dst = Wcat; break;
            case 1: src = OW;  dst = Wcat + 1024 * 1024; break;
            default: src = GWC; dst = GWCt; break;
        }
        const int c0 = (t32 & 31) * 32, r0 = (t32 >> 5) * 32;
        const int x = tid & 31, y = tid >> 5;
        for (int i = y; i < 32; i += 8)
            tile[i][x] = src[(size_t)(r0 + i) * 1024 + c0 + x];
        __syncthreads();
        for (int i = y; i < 32; i += 8)
            dst[(size_t)(c0 + i) * 1024 + r0 + x] = f2bf(tile[x][i]);
    } else {
        const int i = (bid - 44032) * 256 + tid;
        ((float4*)out)[i] = float4{0.f, 0.f, 0.f, 0.f};
    }
}

__device__ __forceinline__ void gl_lds16(const void* g, void* l) {
    __builtin_amdgcn_global_load_lds((const __attribute__((address_space(1))) void*)g,
                                     (__attribute__((address_space(3))) void*)l, 16, 0, 0);
}

// ---------------- GEMM A: WPcat(interleaved) = Pb @ Wcat^T  (128x256 tile, 512 thr) ----------------
// grid 512: xcd=bid&7, q=bid>>3; slab=(q>>3)*8+xcd (64 slabs), colt=q&7 (8 cols).
__global__ __launch_bounds__(512, 4) void gemmA(const ushort_t* __restrict__ A,
                                                const ushort_t* __restrict__ Bt,
                                                ushort_t* __restrict__ C) {
    __shared__ ushort_t smem[12288];      // lA 4096 + lB 8192 elems = 24 KB
    ushort_t* lA = smem;
    ushort_t* lB = smem + 4096;
    const int K = 1024;
    const int xcd = blockIdx.x & 7, q = blockIdx.x >> 3;
    const int tileM = ((q >> 3) * 8 + xcd) * 128;
    const int tileN = (q & 7) * 256;

    const int t = threadIdx.x;
    const int wave = t >> 6, lane = t & 63;
    const int quad = lane >> 4, l16 = lane & 15;
    const int wm = wave >> 2, wn = wave & 3;

    // staging: row rr = lane>>2, slot = lane&3; global seg pre-swizzled so LDS dest
    // stays linear (rule #21). slot(seg,rr) = seg ^ ((rr>>1)&3) -> 8 bank-groups
    // covered per 8 rows (R7/R8 layout, measured conflict-free).
    const int srow = lane >> 2;
    const int sc   = ((lane & 3) ^ ((lane >> 3) & 3)) * 8;
    const ushort_t* Ag  = A  + (size_t)(tileM + wave * 16 + srow) * K + sc;
    const ushort_t* Bg0 = Bt + (size_t)(tileN + wave * 32 + srow) * K + sc;
    const ushort_t* Bg1 = Bg0 + (size_t)16 * K;
    const int loA = wave * 512 + lane * 8;
    const int loB = wave * 1024 + lane * 8;
    const int fro = (l16 * 4 + (quad ^ ((l16 >> 1) & 3))) * 8;

    floatx4 acc[4][4];
#pragma unroll
    for (int i = 0; i < 4; i++)
#pragma unroll
        for (int j = 0; j < 4; j++) acc[i][j] = (floatx4)0.f;

    for (int k0 = 0; k0 < K; k0 += 32) {
        gl_lds16(Ag + k0,  &lA[loA]);
        gl_lds16(Bg0 + k0, &lB[loB]);
        gl_lds16(Bg1 + k0, &lB[loB + 512]);
        __syncthreads();
        short8 af[4], bfr[4];
#pragma unroll
        for (int mi = 0; mi < 4; mi++)
            af[mi] = *(const short8*)&lA[(wm * 4 + mi) * 512 + fro];
#pragma unroll
        for (int ni = 0; ni < 4; ni++)
            bfr[ni] = *(const short8*)&lB[(wn * 4 + ni) * 512 + fro];
#pragma unroll
        for (int mi = 0; mi < 4; mi++)
#pragma unroll
            for (int ni = 0; ni < 4; ni++)
                acc[mi][ni] = __builtin_amdgcn_mfma_f32_16x16x32_bf16(
                    af[mi], bfr[ni], acc[mi][ni], 0, 0, 0);
        __syncthreads();
    }
#pragma unroll
    for (int mi = 0; mi < 4; mi++)
#pragma unroll
        for (int ni = 0; ni < 4; ni++) {
            const int col = tileN + wn * 64 + ni * 16 + l16;
            const int ci = col & 1023, hi = col >> 10;    // interleave: (wp,wpo) per uint32
#pragma unroll
            for (int r = 0; r < 4; r++) {
                const int row = tileM + wm * 64 + mi * 16 + quad * 4 + r;
                C[(size_t)(row * 1024 + ci) * 2 + hi] = f2bf(acc[mi][ni][r]);
            }
        }
}

// ---------------- GEMM B + register-direct fused epilogue (128x256 tile, 512 thr) ----------------
// grid 1024: xcd=bid&7, q=bid>>3; slab=(q>>2)*8+xcd (256 slabs), colt=q&3 (4 cols).
// Lane owns C-fragment rows wm*64+mi*16+quad*4+r, col wn*64+ni*16+l16; it folds
// sigmoid/dot contributions straight out of acc (fp32), reduces across the 16-lane
// quad group, and l16==0 atomicAdds. acc never spills, WC never hits memory.
__global__ __launch_bounds__(512, 4) void gemmB_fused(const ushort_t* __restrict__ Call,
                                                      const ushort_t* __restrict__ GWCt,
                                                      const uint_t* __restrict__ WPcat,
                                                      const float* __restrict__ Gb,
                                                      const float* __restrict__ Ob,
                                                      float* __restrict__ out) {
    __shared__ ushort_t smem[12288];      // 24 KB staging only
    ushort_t* lA = smem;
    ushort_t* lB = smem + 4096;
    const int K = 1024;
    const int xcd = blockIdx.x & 7, q = blockIdx.x >> 3;
    const int tileM = ((q >> 2) * 8 + xcd) * 128;
    const int tileN = (q & 3) * 256;

    const int t = threadIdx.x;
    const int wave = t >> 6, lane = t & 63;
    const int quad = lane >> 4, l16 = lane & 15;
    const int wm = wave >> 2, wn = wave & 3;

    const int srow = lane >> 2;
    const int sc   = ((lane & 3) ^ ((lane >> 3) & 3)) * 8;
    const ushort_t* Ag  = Call + (size_t)(tileM + wave * 16 + srow) * K + sc;
    const ushort_t* Bg0 = GWCt + (size_t)(tileN + wave * 32 + srow) * K + sc;
    const ushort_t* Bg1 = Bg0 + (size_t)16 * K;
    const int loA = wave * 512 + lane * 8;
    const int loB = wave * 1024 + lane * 8;
    const int fro = (l16 * 4 + (quad ^ ((l16 >> 1) & 3))) * 8;

    floatx4 acc[4][4];
#pragma unroll
    for (int i = 0; i < 4; i++)
#pragma unroll
        for (int j = 0; j < 4; j++) acc[i][j] = (floatx4)0.f;

    for (int k0 = 0; k0 < K; k0 += 32) {
        gl_lds16(Ag + k0,  &lA[loA]);
        gl_lds16(Bg0 + k0, &lB[loB]);
        gl_lds16(Bg1 + k0, &lB[loB + 512]);
        __syncthreads();
        short8 af[4], bfr[4];
#pragma unroll
        for (int mi = 0; mi < 4; mi++)
            af[mi] = *(const short8*)&lA[(wm * 4 + mi) * 512 + fro];
#pragma unroll
        for (int ni = 0; ni < 4; ni++)
            bfr[ni] = *(const short8*)&lB[(wn * 4 + ni) * 512 + fro];
#pragma unroll
        for (int mi = 0; mi < 4; mi++)
#pragma unroll
            for (int ni = 0; ni < 4; ni++)
                acc[mi][ni] = __builtin_amdgcn_mfma_f32_16x16x32_bf16(
                    af[mi], bfr[ni], acc[mi][ni], 0, 0, 0);
        __syncthreads();
    }

    // ---- register-direct epilogue ----
    const int kk   = tileM >> 13;                          // choice index k (uniform per block)
    const int b0   = (tileM & 8191) + wm * 64 + quad * 4;  // batch row base (+mi*16+r)
    const int rowg = tileM + wm * 64 + quad * 4;           // Call row base (+mi*16+r)

    float gbv[4], obv[4];
    int   gcol[4];
#pragma unroll
    for (int ni = 0; ni < 4; ni++) {
        gcol[ni] = tileN + wn * 64 + ni * 16 + l16;
        gbv[ni]  = Gb[gcol[ni]];
        obv[ni]  = Ob[gcol[ni]];
    }

#pragma unroll
    for (int mi = 0; mi < 4; mi++) {
        float part[4] = {0.f, 0.f, 0.f, 0.f};
#pragma unroll
        for (int ni = 0; ni < 4; ni++) {
            const uint_t*   wpp = WPcat + (size_t)(b0 + mi * 16) * 1024 + gcol[ni];
            const ushort_t* ckp = Call  + (size_t)(rowg + mi * 16) * 1024 + gcol[ni];
#pragma unroll
            for (int r = 0; r < 4; r++) {
                const uint_t wpair = wpp[(size_t)r * 1024];
                const float wp  = bf2f((unsigned short)(wpair & 0xffffu));
                const float wpo = bf2f((unsigned short)(wpair >> 16));
                const float ck  = bf2f(ckp[(size_t)r * 1024]);
                const float x = wp + acc[mi][ni][r] + gbv[ni];   // WC stays fp32
                const float g = 1.f / (1.f + __expf(-x));
                part[r] += ck * g * (wpo + obv[ni]);
            }
        }
#pragma unroll
        for (int r = 0; r < 4; r++) {                    // reduce across 16-lane quad group
            part[r] += __shfl_xor(part[r], 1);
            part[r] += __shfl_xor(part[r], 2);
            part[r] += __shfl_xor(part[r], 4);
            part[r] += __shfl_xor(part[r], 8);
        }
        if (l16 == 0) {
#pragma unroll
            for (int r = 0; r < 4; r++)
                atomicAdd(&out[(size_t)(b0 + mi * 16 + r) * 4 + kk], part[r]);
        }
    }
}

extern "C" void kernel_launch(void* const* d_in, const int* in_sizes, int n_in,
                              void* d_out, int out_size, void* d_ws, size_t ws_size,
                              hipStream_t stream) {
    (void)in_sizes; (void)n_in; (void)out_size; (void)ws_size;
    const float* P   = (const float*)d_in[0];
    const float* C1  = (const float*)d_in[1];
    const float* C2  = (const float*)d_in[2];
    const float* C3  = (const float*)d_in[3];
    const float* C4  = (const float*)d_in[4];
    const float* GWP = (const float*)d_in[5];
    const float* GWC = (const float*)d_in[6];
    const float* Gb  = (const float*)d_in[7];
    const float* OW  = (const float*)d_in[8];
    const float* Ob  = (const float*)d_in[9];
    float* out = (float*)d_out;

    // workspace (bf16): Pb 16MiB | Call 64MiB | Wcat 4MiB | GWCt 2MiB | WPcat 32MiB
    char* ws = (char*)d_ws;
    ushort_t* Pb    = (ushort_t*)(ws);
    ushort_t* Call  = (ushort_t*)(ws + (16u << 20));
    ushort_t* Wcat  = (ushort_t*)(ws + (80u << 20));
    ushort_t* GWCt  = (ushort_t*)(ws + (84u << 20));
    ushort_t* WPcat = (ushort_t*)(ws + (86u << 20));

    prep_kernel<<<44064, 256, 0, stream>>>(P, C1, C2, C3, C4, GWP, OW, GWC,
                                           Pb, Call, Wcat, GWCt, out);
    gemmA<<<512, 512, 0, stream>>>(Pb, Wcat, WPcat);
    gemmB_fused<<<1024, 512, 0, stream>>>(Call, GWCt, (const uint_t*)WPcat, Gb, Ob, out);
}